// Round 15
// baseline (141.347 us; speedup 1.0000x reference)
//
#include <hip/hip_runtime.h>
#include <hip/hip_bf16.h>
#include <math.h>

// B=2, S=4096, H=512, NH=8, HD=64. M = B*S = 8192.
// bf16 MFMA 16x16x32, fp32 accumulate. Softmax in exp2 domain (Q pre-scaled
// by 0.125*log2(e)). No running max: scores bounded, P=exp2(s), normalize at
// the end. Attention = round-9 verified kernel. The X fp32->bf16 conversion
// is FUSED into gemm<0>'s A-staging (linear fp32 loads -> cvt_pk -> swizzled
// ds_write; same LDS granule mapping as the pre-swizzled global_load_lds
// path, so fragment reads are unchanged and the math is bit-identical).

typedef __bf16 bf16;
typedef __bf16 bf16x2v __attribute__((ext_vector_type(2)));
typedef __bf16 bf16x4 __attribute__((ext_vector_type(4)));
typedef __bf16 bf16x8 __attribute__((ext_vector_type(8)));
typedef float  f32x4  __attribute__((ext_vector_type(4)));
typedef unsigned int u32x2 __attribute__((ext_vector_type(2)));
typedef unsigned int u32x4 __attribute__((ext_vector_type(4)));

#define MFMA16(a, b, c) __builtin_amdgcn_mfma_f32_16x16x32_bf16((a), (b), (c), 0, 0, 0)

__device__ __forceinline__ void gll16(const bf16* g, bf16* l) {
    __builtin_amdgcn_global_load_lds(
        (const __attribute__((address_space(1))) void*)g,
        (__attribute__((address_space(3))) void*)l, 16, 0, 0);
}

__device__ __forceinline__ unsigned int cvtpk(float lo, float hi) {
    unsigned int r;
    asm("v_cvt_pk_bf16_f32 %0, %1, %2" : "=v"(r) : "v"(lo), "v"(hi));
    return r;
}

// ---------------- fp32 -> bf16 weight convert ----------------
__global__ __launch_bounds__(256) void cvt_w4(const float* __restrict__ a,
                                              const float* __restrict__ b,
                                              const float* __restrict__ c,
                                              const float* __restrict__ d,
                                              bf16* __restrict__ out) {
    const int y = blockIdx.y;
    const float* src = (y == 0) ? a : (y == 1) ? b : (y == 2) ? c : d;
    int i = (blockIdx.x * 256 + threadIdx.x) * 4;
    float4 v = *reinterpret_cast<const float4*>(src + i);
    bf16x4 o = {(bf16)v.x, (bf16)v.y, (bf16)v.z, (bf16)v.w};
    *reinterpret_cast<bf16x4*>(out + y * 262144 + i) = o;
}

// ---------------- GEMM: C = A[M,K] * W[N,K]^T + bias ----------------
// MODE 0: QKV projection (768 blocks). A = X fp32, converted in-staging.
//         z: 0=Q (scaled 0.125*log2e, head-split), 1=K (head-split),
//         2=V transposed per head: Vt[bh][d][s].
// MODE 1: output projection (256 blocks), A bf16 via global_load_lds,
//         fp32 out [M][512].
template <int MODE>
__global__ __launch_bounds__(256) void gemm_bt(const float* __restrict__ Af,
                                               const bf16* __restrict__ A,
                                               const bf16* __restrict__ W,
                                               const float* __restrict__ b0,
                                               const float* __restrict__ b1,
                                               const float* __restrict__ b2,
                                               bf16* __restrict__ dstbf,
                                               float* __restrict__ dstf) {
    __shared__ bf16 sA[128 * 64];
    __shared__ bf16 sB[128 * 64];

    const int tid = threadIdx.x;
    const int w   = tid >> 6;
    const int l   = tid & 63;

    // XCD-grouping remap (pure permutation of block ids)
    int bx, by, bz;
    if (MODE == 0) {
        int lin = (blockIdx.x & 7) * 96 + (blockIdx.x >> 3);   // 768 blocks
        const int rem = lin % 12;
        bx = rem & 3; bz = rem >> 2; by = lin / 12;
    } else {
        int lin = (blockIdx.x & 7) * 32 + (blockIdx.x >> 3);   // 256 blocks
        bx = lin & 3; by = lin >> 2; bz = 0;
    }
    const int m0 = by * 128;
    const int n0 = bx * 128;
    const int z  = bz;

    const bf16*  Wz   = (MODE == 0) ? (W + z * 262144) : W;
    const float* bias = (MODE == 0) ? (z == 0 ? b0 : (z == 1 ? b1 : b2)) : b0;
    const float  scale = (MODE == 0 && z == 0) ? 0.125f * 1.4426950408889634f : 1.0f;

    const int wr = (w >> 1) * 64, wc = (w & 1) * 64;
    const int fr = l & 15, fg = l >> 4;

    // staging geometry
    const int srow0 = tid >> 3;                  // 0..31
    const int sgr   = (tid & 7) ^ (srow0 & 7);   // pre-swizzled source granule
    const int ldso  = srow0 * 64 + (tid & 7) * 8;
    // swizzled LDS write slot for the fused-convert path (same mapping:
    // LDS position p holds global granule p^(row&7))
    const int lws   = srow0 * 64 + (sgr << 3);

    f32x4 acc[4][4];
    const f32x4 zero = {0.f, 0.f, 0.f, 0.f};
#pragma unroll
    for (int i = 0; i < 4; i++)
#pragma unroll
        for (int j = 0; j < 4; j++) acc[i][j] = zero;

    for (int kt = 0; kt < 512; kt += 64) {
        __syncthreads();
        if constexpr (MODE == 0) {
            // A: linear-coalesced fp32 loads (issued first, overlap W loads)
            float4 xa[4][2];
#pragma unroll
            for (int p = 0; p < 4; p++) {
                const float* src =
                    Af + (size_t)(m0 + srow0 + 32 * p) * 512 + kt + (tid & 7) * 8;
                xa[p][0] = *reinterpret_cast<const float4*>(src);
                xa[p][1] = *reinterpret_cast<const float4*>(src + 4);
            }
#pragma unroll
            for (int p = 0; p < 4; p++)
                gll16(Wz + (n0 + srow0 + 32 * p) * 512 + kt + sgr * 8,
                      &sB[p * 2048 + ldso]);
#pragma unroll
            for (int p = 0; p < 4; p++) {
                u32x4 u = {cvtpk(xa[p][0].x, xa[p][0].y),
                           cvtpk(xa[p][0].z, xa[p][0].w),
                           cvtpk(xa[p][1].x, xa[p][1].y),
                           cvtpk(xa[p][1].z, xa[p][1].w)};
                *reinterpret_cast<u32x4*>(&sA[p * 2048 + lws]) = u;
            }
        } else {
#pragma unroll
            for (int p = 0; p < 4; p++) {
                const int row = srow0 + 32 * p;
                gll16(A  + (m0 + row) * 512 + kt + sgr * 8, &sA[p * 2048 + ldso]);
                gll16(Wz + (n0 + row) * 512 + kt + sgr * 8, &sB[p * 2048 + ldso]);
            }
        }
        __syncthreads();

#pragma unroll
        for (int ks = 0; ks < 2; ks++) {
            bf16x8 af[4], bfg[4];
#pragma unroll
            for (int mi = 0; mi < 4; mi++)
                af[mi] = *reinterpret_cast<const bf16x8*>(
                    &sA[(wr + mi * 16 + fr) * 64 + (((4 * ks + fg) ^ (fr & 7)) << 3)]);
#pragma unroll
            for (int ni = 0; ni < 4; ni++)
                bfg[ni] = *reinterpret_cast<const bf16x8*>(
                    &sB[(wc + ni * 16 + fr) * 64 + (((4 * ks + fg) ^ (fr & 7)) << 3)]);
#pragma unroll
            for (int mi = 0; mi < 4; mi++)
#pragma unroll
                for (int ni = 0; ni < 4; ni++)
                    acc[mi][ni] = MFMA16(af[mi], bfg[ni], acc[mi][ni]);
        }
    }

#pragma unroll
    for (int mi = 0; mi < 4; mi++) {
#pragma unroll
        for (int ni = 0; ni < 4; ni++) {
            const int gcol = n0 + wc + ni * 16 + fr;
            const float bc = bias[gcol];
#pragma unroll
            for (int r = 0; r < 4; r++) {
                const int grow = m0 + wr + mi * 16 + fg * 4 + r;
                float v = acc[mi][ni][r] + bc;
                if (MODE == 0) {
                    v *= scale;
                    const int bb = grow >> 12, s = grow & 4095;
                    const int hh = gcol >> 6, dd = gcol & 63;
                    size_t idx;
                    if (z == 2) {
                        idx = (size_t)2 * 4194304 +
                              ((size_t)((bb * 8 + hh) * 64 + dd)) * 4096 + s;
                    } else {
                        idx = (size_t)z * 4194304 +
                              ((size_t)((bb * 8 + hh) * 4096 + s) << 6) + dd;
                    }
                    dstbf[idx] = (bf16)v;
                } else {
                    dstf[grow * 512 + gcol] = v;
                }
            }
        }
    }
}

// ---------------- Flash attention (round-9 verified) ----------------
// 256 threads = 4 waves; each wave owns 32 q-rows (2 subtiles); block = 128
// q-rows x all 4096 keys. grid 512 blocks, XCD-remapped (2 heads per XCD).
// KV tile 64, double-buffered global_load_lds. P in registers via
// cvt_pk_bf16_f32 + permlane32/16_swap. No running max. Per iteration: one
// 36-MFMA cluster {QK[t], PV[t-1]}, then vf[t] ds_read + softmax[t].
__global__ __launch_bounds__(256, 2) void attn_kernel(const bf16* __restrict__ Q,
                                                      const bf16* __restrict__ K,
                                                      const bf16* __restrict__ Vt,
                                                      bf16* __restrict__ ctx) {
    __shared__ bf16 sKb[2][4096];     // [kv][d], 16B-granule XOR-swizzled
    __shared__ bf16 sVb[2][4096];     // [d][kv], swizzled

    const int tid = threadIdx.x;
    const int w   = tid >> 6;
    const int l   = tid & 63;
    const int fr  = l & 15, fg = l >> 4;

    // XCD-aware remap: 512 blocks -> 64 consecutive per XCD (= 2 heads)
    int n = blockIdx.y * 32 + blockIdx.x;
    n = (n & 7) * 64 + (n >> 3);
    const int bh  = n >> 5;
    const int q0  = (n & 31) * 128;
    const size_t base = (size_t)bh * 262144;

    // staging: thread -> granule (tid&7) of row (tid>>3), 2 passes of 32 rows
    const int srow0 = tid >> 3;
    const int sgr   = (tid & 7) ^ (srow0 & 7);
    const int ldso  = srow0 * 64 + (tid & 7) * 8;

    // hoisted fragment-read offsets (elements)
    const int ko0 = fr * 64 + (((0 + fg) ^ (fr & 7)) << 3);
    const int ko1 = fr * 64 + (((4 + fg) ^ (fr & 7)) << 3);

#define STAGE(buf, tt)                                                              \
    do {                                                                            \
        _Pragma("unroll")                                                           \
        for (int p = 0; p < 2; p++) {                                               \
            const int row_ = srow0 + 32 * p;                                        \
            gll16(K  + base + (size_t)((tt) + row_) * 64 + sgr * 8,                 \
                  &sKb[buf][p * 2048 + ldso]);                                      \
            gll16(Vt + base + (size_t)row_ * 4096 + (tt) + sgr * 8,                 \
                  &sVb[buf][p * 2048 + ldso]);                                      \
        }                                                                           \
    } while (0)

#define QK_TILE(kb_)                                                                \
    do {                                                                            \
        _Pragma("unroll")                                                           \
        for (int kvb = 0; kvb < 4; kvb++) {                                         \
            const bf16x8 kf0 = *reinterpret_cast<const bf16x8*>((kb_) + ko0 + kvb * 1024); \
            const bf16x8 kf1 = *reinterpret_cast<const bf16x8*>((kb_) + ko1 + kvb * 1024); \
            _Pragma("unroll")                                                       \
            for (int qb = 0; qb < 2; qb++) {                                        \
                sc[kvb][qb] = MFMA16(kf0, qf[0][qb], zero);                         \
                sc[kvb][qb] = MFMA16(kf1, qf[1][qb], sc[kvb][qb]);                  \
            }                                                                       \
        }                                                                           \
    } while (0)

#define PV_TILE()                                                                   \
    do {                                                                            \
        _Pragma("unroll")                                                           \
        for (int ks = 0; ks < 2; ks++) {                                            \
            _Pragma("unroll")                                                       \
            for (int qb = 0; qb < 2; qb++)                                          \
                lacc[qb] = MFMA16(ones, pf[ks][qb], lacc[qb]);                      \
            _Pragma("unroll")                                                       \
            for (int db = 0; db < 4; db++)                                          \
                _Pragma("unroll")                                                   \
                for (int qb = 0; qb < 2; qb++)                                      \
                    o[db][qb] = MFMA16(vf[ks][db], pf[ks][qb], o[db][qb]);          \
        }                                                                           \
    } while (0)

#define VF_READ(vb_)                                                                \
    do {                                                                            \
        _Pragma("unroll")                                                           \
        for (int db = 0; db < 4; db++) {                                            \
            vf[0][db] = *reinterpret_cast<const bf16x8*>((vb_) + ko0 + db * 1024);  \
            vf[1][db] = *reinterpret_cast<const bf16x8*>((vb_) + ko1 + db * 1024);  \
        }                                                                           \
    } while (0)

#define SOFTMAX_PACK()                                                              \
    do {                                                                            \
        _Pragma("unroll")                                                           \
        for (int qb = 0; qb < 2; qb++) {                                            \
            unsigned int c[4][2];                                                   \
            _Pragma("unroll")                                                       \
            for (int kvb = 0; kvb < 4; kvb++) {                                     \
                const float p0 = __builtin_amdgcn_exp2f(sc[kvb][qb][0]);            \
                const float p1 = __builtin_amdgcn_exp2f(sc[kvb][qb][1]);            \
                const float p2 = __builtin_amdgcn_exp2f(sc[kvb][qb][2]);            \
                const float p3 = __builtin_amdgcn_exp2f(sc[kvb][qb][3]);            \
                c[kvb][0] = cvtpk(p0, p1);                                          \
                c[kvb][1] = cvtpk(p2, p3);                                          \
            }                                                                       \
            _Pragma("unroll")                                                       \
            for (int ks = 0; ks < 2; ks++) {                                        \
                unsigned int a0 = c[2 * ks][0], b0 = c[2 * ks + 1][0];              \
                unsigned int a1 = c[2 * ks][1], b1 = c[2 * ks + 1][1];              \
                asm("v_permlane32_swap_b32 %0, %1" : "+v"(a0), "+v"(b0));           \
                asm("v_permlane16_swap_b32 %0, %1" : "+v"(a0), "+v"(b0));           \
                asm("v_permlane32_swap_b32 %0, %1" : "+v"(a1), "+v"(b1));           \
                asm("v_permlane16_swap_b32 %0, %1" : "+v"(a1), "+v"(b1));           \
                u32x4 uu = {a0, a1, b0, b1};                                        \
                pf[ks][qb] = __builtin_bit_cast(bf16x8, uu);                        \
            }                                                                       \
        }                                                                           \
    } while (0)

#define BODY(KBUF, tt)                                                              \
    do {                                                                            \
        __syncthreads();                                                            \
        STAGE((KBUF) ^ 1, (tt) + 64);                                               \
        __builtin_amdgcn_s_setprio(1);                                              \
        QK_TILE(sKb[KBUF]);                                                         \
        PV_TILE();                                                                  \
        __builtin_amdgcn_s_setprio(0);                                              \
        VF_READ(sVb[KBUF]);                                                         \
        SOFTMAX_PACK();                                                             \
    } while (0)

    // Q fragments (B-operand: col=q=fr, k=d), 2 q-subtiles per wave
    bf16x8 qf[2][2];
#pragma unroll
    for (int qb = 0; qb < 2; qb++)
#pragma unroll
        for (int ks = 0; ks < 2; ks++)
            qf[ks][qb] = *reinterpret_cast<const bf16x8*>(
                Q + base + (size_t)(q0 + 32 * w + 16 * qb + fr) * 64 + ks * 32 + fg * 8);

    const bf16 one = (bf16)1.0f;
    const bf16x8 ones = {one, one, one, one, one, one, one, one};

    const f32x4 zero = {0.f, 0.f, 0.f, 0.f};
    f32x4 o[4][2];
#pragma unroll
    for (int db = 0; db < 4; db++)
#pragma unroll
        for (int qb = 0; qb < 2; qb++) o[db][qb] = zero;
    f32x4 lacc[2] = {zero, zero};

    f32x4  sc[4][2];
    bf16x8 vf[2][4];
    bf16x8 pf[2][2];

    // ---- prologue: stage tile 0, compute QK[0] + vf[0] + softmax[0] ----
    STAGE(0, 0);
    __syncthreads();                 // tile 0 ready
    STAGE(1, 64);
    QK_TILE(sKb[0]);
    VF_READ(sVb[0]);
    SOFTMAX_PACK();

    // ---- main loop: tiles 1..62 as 31 unrolled pairs (static buffers) ----
    int t = 64;
    for (int i = 0; i < 31; i++, t += 128) {
        BODY(1, t);                  // odd tile in buf1
        BODY(0, t + 64);             // even tile in buf0
    }

    // ---- tail: tile 63 (buf1, no further staging), then final PV ----
    __syncthreads();
    __builtin_amdgcn_s_setprio(1);
    QK_TILE(sKb[1]);
    PV_TILE();
    __builtin_amdgcn_s_setprio(0);
    VF_READ(sVb[1]);
    SOFTMAX_PACK();
    __builtin_amdgcn_s_setprio(1);
    PV_TILE();
    __builtin_amdgcn_s_setprio(0);

    // epilogue: lane owns q = q0+32w+16qb+fr (col), d = 16db+4fg+r (rows)
    const int bb = bh >> 3, hh = bh & 7;
#pragma unroll
    for (int qb = 0; qb < 2; qb++) {
        const float inv = 1.0f / lacc[qb][0];
        const int s = q0 + 32 * w + 16 * qb + fr;
#pragma unroll
        for (int db = 0; db < 4; db++) {
            u32x2 pr = {cvtpk(o[db][qb][0] * inv, o[db][qb][1] * inv),
                        cvtpk(o[db][qb][2] * inv, o[db][qb][3] * inv)};
            *reinterpret_cast<u32x2*>(
                &ctx[((size_t)(bb * 4096 + s)) * 512 + hh * 64 + db * 16 + 4 * fg]) = pr;
        }
    }
#undef STAGE
#undef QK_TILE
#undef PV_TILE
#undef VF_READ
#undef SOFTMAX_PACK
#undef BODY
}

// ---------------- launch ----------------
extern "C" void kernel_launch(void* const* d_in, const int* in_sizes, int n_in,
                              void* d_out, int out_size, void* d_ws, size_t ws_size,
                              hipStream_t stream) {
    const float* X  = (const float*)d_in[0];
    const float* Wq = (const float*)d_in[1];
    const float* bq = (const float*)d_in[2];
    const float* Wk = (const float*)d_in[3];
    const float* bk = (const float*)d_in[4];
    const float* Wv = (const float*)d_in[5];
    const float* bv = (const float*)d_in[6];
    const float* Wo = (const float*)d_in[7];
    const float* bo = (const float*)d_in[8];
    float* out = (float*)d_out;

    bf16* ws  = (bf16*)d_ws;
    bf16* Xbf = ws;                    // (kept for layout; unused now)
    bf16* Wqb = Xbf + 4194304;         // 4 x 262,144 contiguous (Wq,Wk,Wv,Wo)
    bf16* Qb  = Wqb + 4 * 262144;      // Q / K / Vt each 4,194,304
    bf16* Kb  = Qb + 4194304;
    bf16* Vtb = Kb + 4194304;
    bf16* Ctx = Vtb + 4194304;

    cvt_w4<<<dim3(256, 4), 256, 0, stream>>>(Wq, Wk, Wv, Wo, Wqb);

    // projections (X converted in-staging): Q (log2-scaled, head-split),
    // K (head-split), V -> Vt[bh][d][s]
    gemm_bt<0><<<768, 256, 0, stream>>>(X, nullptr, Wqb, bq, bk, bv, Qb, nullptr);

    // flash attention -> ctx bf16 [B][S][H]
    attn_kernel<<<dim3(32, 16), 256, 0, stream>>>(Qb, Kb, Vtb, Ctx);

    // output projection -> fp32 d_out
    gemm_bt<1><<<256, 256, 0, stream>>>(nullptr, Ctx, Wqb + 3 * 262144, bo,
                                        nullptr, nullptr, nullptr, out);
}

// Round 16
// 136.270 us; speedup vs baseline: 1.0373x; 1.0373x over previous
//
#include <hip/hip_runtime.h>
#include <hip/hip_bf16.h>
#include <math.h>

// B=2, S=4096, H=512, NH=8, HD=64. M = B*S = 8192.
// bf16 MFMA 16x16x32, fp32 accumulate. Softmax in exp2 domain (Q pre-scaled
// by 0.125*log2(e)). No running max: scores bounded, P=exp2(s), normalize at
// the end. Attention: 3-stage single-wave pipeline — iteration t issues
// QK[t] (MFMA) INTERLEAVED with softmax[t-1] (exp2/cvtpk, independent),
// then permlane, PV[t-1], vf[t]. sc is double-buffered (scA/scB).

typedef __bf16 bf16;
typedef __bf16 bf16x2v __attribute__((ext_vector_type(2)));
typedef __bf16 bf16x4 __attribute__((ext_vector_type(4)));
typedef __bf16 bf16x8 __attribute__((ext_vector_type(8)));
typedef float  f32x4  __attribute__((ext_vector_type(4)));
typedef unsigned int u32x2 __attribute__((ext_vector_type(2)));
typedef unsigned int u32x4 __attribute__((ext_vector_type(4)));

#define MFMA16(a, b, c) __builtin_amdgcn_mfma_f32_16x16x32_bf16((a), (b), (c), 0, 0, 0)

__device__ __forceinline__ void gll16(const bf16* g, bf16* l) {
    __builtin_amdgcn_global_load_lds(
        (const __attribute__((address_space(1))) void*)g,
        (__attribute__((address_space(3))) void*)l, 16, 0, 0);
}

__device__ __forceinline__ unsigned int cvtpk(float lo, float hi) {
    unsigned int r;
    asm("v_cvt_pk_bf16_f32 %0, %1, %2" : "=v"(r) : "v"(lo), "v"(hi));
    return r;
}

// ---------------- fp32 -> bf16 converts ----------------
__global__ __launch_bounds__(256) void cvt_f32_bf16(const float* __restrict__ src,
                                                    bf16* __restrict__ dst, int n) {
    int i = (blockIdx.x * 256 + threadIdx.x) * 4;
    if (i >= n) return;
    float4 v = *reinterpret_cast<const float4*>(src + i);
    bf16x4 o = {(bf16)v.x, (bf16)v.y, (bf16)v.z, (bf16)v.w};
    *reinterpret_cast<bf16x4*>(dst + i) = o;
}

__global__ __launch_bounds__(256) void cvt_w4(const float* __restrict__ a,
                                              const float* __restrict__ b,
                                              const float* __restrict__ c,
                                              const float* __restrict__ d,
                                              bf16* __restrict__ out) {
    const int y = blockIdx.y;
    const float* src = (y == 0) ? a : (y == 1) ? b : (y == 2) ? c : d;
    int i = (blockIdx.x * 256 + threadIdx.x) * 4;
    float4 v = *reinterpret_cast<const float4*>(src + i);
    bf16x4 o = {(bf16)v.x, (bf16)v.y, (bf16)v.z, (bf16)v.w};
    *reinterpret_cast<bf16x4*>(out + y * 262144 + i) = o;
}

// ---------------- GEMM: C = A[M,K] * W[N,K]^T + bias (round-14 version) ----
template <int MODE>
__global__ __launch_bounds__(256) void gemm_bt(const bf16* __restrict__ A,
                                               const bf16* __restrict__ W,
                                               const float* __restrict__ b0,
                                               const float* __restrict__ b1,
                                               const float* __restrict__ b2,
                                               bf16* __restrict__ dstbf,
                                               float* __restrict__ dstf) {
    __shared__ bf16 sA[128 * 64];
    __shared__ bf16 sB[128 * 64];

    const int tid = threadIdx.x;
    const int w   = tid >> 6;
    const int l   = tid & 63;

    int bx, by, bz;
    if (MODE == 0) {
        int lin = (blockIdx.x & 7) * 96 + (blockIdx.x >> 3);   // 768 blocks
        const int rem = lin % 12;
        bx = rem & 3; bz = rem >> 2; by = lin / 12;
    } else {
        int lin = (blockIdx.x & 7) * 32 + (blockIdx.x >> 3);   // 256 blocks
        bx = lin & 3; by = lin >> 2; bz = 0;
    }
    const int m0 = by * 128;
    const int n0 = bx * 128;
    const int z  = bz;

    const bf16*  Wz   = (MODE == 0) ? (W + z * 262144) : W;
    const float* bias = (MODE == 0) ? (z == 0 ? b0 : (z == 1 ? b1 : b2)) : b0;
    const float  scale = (MODE == 0 && z == 0) ? 0.125f * 1.4426950408889634f : 1.0f;

    const int wr = (w >> 1) * 64, wc = (w & 1) * 64;
    const int fr = l & 15, fg = l >> 4;

    const int srow0 = tid >> 3;
    const int sgr   = (tid & 7) ^ (srow0 & 7);
    const int ldso  = srow0 * 64 + (tid & 7) * 8;

    f32x4 acc[4][4];
    const f32x4 zero = {0.f, 0.f, 0.f, 0.f};
#pragma unroll
    for (int i = 0; i < 4; i++)
#pragma unroll
        for (int j = 0; j < 4; j++) acc[i][j] = zero;

    for (int kt = 0; kt < 512; kt += 64) {
        __syncthreads();
#pragma unroll
        for (int p = 0; p < 4; p++) {
            const int row = srow0 + 32 * p;
            gll16(A  + (m0 + row) * 512 + kt + sgr * 8, &sA[p * 2048 + ldso]);
            gll16(Wz + (n0 + row) * 512 + kt + sgr * 8, &sB[p * 2048 + ldso]);
        }
        __syncthreads();

#pragma unroll
        for (int ks = 0; ks < 2; ks++) {
            bf16x8 af[4], bfg[4];
#pragma unroll
            for (int mi = 0; mi < 4; mi++)
                af[mi] = *reinterpret_cast<const bf16x8*>(
                    &sA[(wr + mi * 16 + fr) * 64 + (((4 * ks + fg) ^ (fr & 7)) << 3)]);
#pragma unroll
            for (int ni = 0; ni < 4; ni++)
                bfg[ni] = *reinterpret_cast<const bf16x8*>(
                    &sB[(wc + ni * 16 + fr) * 64 + (((4 * ks + fg) ^ (fr & 7)) << 3)]);
#pragma unroll
            for (int mi = 0; mi < 4; mi++)
#pragma unroll
                for (int ni = 0; ni < 4; ni++)
                    acc[mi][ni] = MFMA16(af[mi], bfg[ni], acc[mi][ni]);
        }
    }

#pragma unroll
    for (int mi = 0; mi < 4; mi++) {
#pragma unroll
        for (int ni = 0; ni < 4; ni++) {
            const int gcol = n0 + wc + ni * 16 + fr;
            const float bc = bias[gcol];
#pragma unroll
            for (int r = 0; r < 4; r++) {
                const int grow = m0 + wr + mi * 16 + fg * 4 + r;
                float v = acc[mi][ni][r] + bc;
                if (MODE == 0) {
                    v *= scale;
                    const int bb = grow >> 12, s = grow & 4095;
                    const int hh = gcol >> 6, dd = gcol & 63;
                    size_t idx;
                    if (z == 2) {
                        idx = (size_t)2 * 4194304 +
                              ((size_t)((bb * 8 + hh) * 64 + dd)) * 4096 + s;
                    } else {
                        idx = (size_t)z * 4194304 +
                              ((size_t)((bb * 8 + hh) * 4096 + s) << 6) + dd;
                    }
                    dstbf[idx] = (bf16)v;
                } else {
                    dstf[grow * 512 + gcol] = v;
                }
            }
        }
    }
}

// ---------------- Flash attention (3-stage pipelined) ----------------
// 256 threads = 4 waves; each wave owns 32 q-rows (2 subtiles); block = 128
// q-rows x 4096 keys. grid 512 blocks, XCD-remapped. KV tile 64, dbuf
// global_load_lds. Per body (tile t): {QK[t] MFMA interleaved with
// softmax[t-1] exp2/cvtpk (independent)} -> permlane -> PV[t-1] -> vf[t].
__global__ __launch_bounds__(256, 2) void attn_kernel(const bf16* __restrict__ Q,
                                                      const bf16* __restrict__ K,
                                                      const bf16* __restrict__ Vt,
                                                      bf16* __restrict__ ctx) {
    __shared__ bf16 sKb[2][4096];     // [kv][d], 16B-granule XOR-swizzled
    __shared__ bf16 sVb[2][4096];     // [d][kv], swizzled

    const int tid = threadIdx.x;
    const int w   = tid >> 6;
    const int l   = tid & 63;
    const int fr  = l & 15, fg = l >> 4;

    // XCD-aware remap: 512 blocks -> 64 consecutive per XCD (= 2 heads)
    int n = blockIdx.y * 32 + blockIdx.x;
    n = (n & 7) * 64 + (n >> 3);
    const int bh  = n >> 5;
    const int q0  = (n & 31) * 128;
    const size_t base = (size_t)bh * 262144;

    const int srow0 = tid >> 3;
    const int sgr   = (tid & 7) ^ (srow0 & 7);
    const int ldso  = srow0 * 64 + (tid & 7) * 8;

    const int ko0 = fr * 64 + (((0 + fg) ^ (fr & 7)) << 3);
    const int ko1 = fr * 64 + (((4 + fg) ^ (fr & 7)) << 3);

#define STAGE(buf, tt)                                                              \
    do {                                                                            \
        _Pragma("unroll")                                                           \
        for (int p = 0; p < 2; p++) {                                               \
            const int row_ = srow0 + 32 * p;                                        \
            gll16(K  + base + (size_t)((tt) + row_) * 64 + sgr * 8,                 \
                  &sKb[buf][p * 2048 + ldso]);                                      \
            gll16(Vt + base + (size_t)row_ * 4096 + (tt) + sgr * 8,                 \
                  &sVb[buf][p * 2048 + ldso]);                                      \
        }                                                                           \
    } while (0)

// QK of current tile into SCN, interleaved with exp2/cvtpk of SCO (prev tile)
#define QKSM_TILE(kb_, SCN, SCO)                                                    \
    do {                                                                            \
        _Pragma("unroll")                                                           \
        for (int kvb = 0; kvb < 4; kvb++) {                                         \
            const bf16x8 kf0 = *reinterpret_cast<const bf16x8*>((kb_) + ko0 + kvb * 1024); \
            const bf16x8 kf1 = *reinterpret_cast<const bf16x8*>((kb_) + ko1 + kvb * 1024); \
            _Pragma("unroll")                                                       \
            for (int qb = 0; qb < 2; qb++) {                                        \
                SCN[kvb][qb] = MFMA16(kf0, qf[0][qb], zero);                        \
                SCN[kvb][qb] = MFMA16(kf1, qf[1][qb], SCN[kvb][qb]);                \
            }                                                                       \
            _Pragma("unroll")                                                       \
            for (int qb = 0; qb < 2; qb++) {                                        \
                cc[qb][kvb][0] = cvtpk(__builtin_amdgcn_exp2f(SCO[kvb][qb][0]),     \
                                       __builtin_amdgcn_exp2f(SCO[kvb][qb][1]));    \
                cc[qb][kvb][1] = cvtpk(__builtin_amdgcn_exp2f(SCO[kvb][qb][2]),     \
                                       __builtin_amdgcn_exp2f(SCO[kvb][qb][3]));    \
            }                                                                       \
        }                                                                           \
    } while (0)

// permlane redistribution: cc -> pf
#define PERMPACK()                                                                  \
    do {                                                                            \
        _Pragma("unroll")                                                           \
        for (int qb = 0; qb < 2; qb++) {                                            \
            _Pragma("unroll")                                                       \
            for (int ks = 0; ks < 2; ks++) {                                        \
                unsigned int a0 = cc[qb][2 * ks][0], b0 = cc[qb][2 * ks + 1][0];    \
                unsigned int a1 = cc[qb][2 * ks][1], b1 = cc[qb][2 * ks + 1][1];    \
                asm("v_permlane32_swap_b32 %0, %1" : "+v"(a0), "+v"(b0));           \
                asm("v_permlane16_swap_b32 %0, %1" : "+v"(a0), "+v"(b0));           \
                asm("v_permlane32_swap_b32 %0, %1" : "+v"(a1), "+v"(b1));           \
                asm("v_permlane16_swap_b32 %0, %1" : "+v"(a1), "+v"(b1));           \
                u32x4 uu = {a0, a1, b0, b1};                                        \
                pf[ks][qb] = __builtin_bit_cast(bf16x8, uu);                        \
            }                                                                       \
        }                                                                           \
    } while (0)

#define PV_TILE()                                                                   \
    do {                                                                            \
        _Pragma("unroll")                                                           \
        for (int ks = 0; ks < 2; ks++) {                                            \
            _Pragma("unroll")                                                       \
            for (int qb = 0; qb < 2; qb++)                                          \
                lacc[qb] = MFMA16(ones, pf[ks][qb], lacc[qb]);                      \
            _Pragma("unroll")                                                       \
            for (int db = 0; db < 4; db++)                                          \
                _Pragma("unroll")                                                   \
                for (int qb = 0; qb < 2; qb++)                                      \
                    o[db][qb] = MFMA16(vf[ks][db], pf[ks][qb], o[db][qb]);          \
        }                                                                           \
    } while (0)

#define VF_READ(vb_)                                                                \
    do {                                                                            \
        _Pragma("unroll")                                                           \
        for (int db = 0; db < 4; db++) {                                            \
            vf[0][db] = *reinterpret_cast<const bf16x8*>((vb_) + ko0 + db * 1024);  \
            vf[1][db] = *reinterpret_cast<const bf16x8*>((vb_) + ko1 + db * 1024);  \
        }                                                                           \
    } while (0)

// full softmax of SC (exp2+cvtpk+permlane) -> pf  (tail only)
#define SOFTMAX_FULL(SC)                                                            \
    do {                                                                            \
        _Pragma("unroll")                                                           \
        for (int qb = 0; qb < 2; qb++)                                              \
            _Pragma("unroll")                                                       \
            for (int kvb = 0; kvb < 4; kvb++) {                                     \
                cc[qb][kvb][0] = cvtpk(__builtin_amdgcn_exp2f(SC[kvb][qb][0]),      \
                                       __builtin_amdgcn_exp2f(SC[kvb][qb][1]));     \
                cc[qb][kvb][1] = cvtpk(__builtin_amdgcn_exp2f(SC[kvb][qb][2]),      \
                                       __builtin_amdgcn_exp2f(SC[kvb][qb][3]));     \
            }                                                                       \
        PERMPACK();                                                                 \
    } while (0)

// body for tile tt: QK[tt] || SM[tt-1] -> pf; PV[tt-1]; vf[tt]
#define BODY(KBUF, tt, SCN, SCO)                                                    \
    do {                                                                            \
        __syncthreads();                                                            \
        STAGE((KBUF) ^ 1, (tt) + 64);                                               \
        __builtin_amdgcn_s_setprio(1);                                              \
        QKSM_TILE(sKb[KBUF], SCN, SCO);                                             \
        PERMPACK();                                                                 \
        PV_TILE();                                                                  \
        __builtin_amdgcn_s_setprio(0);                                              \
        VF_READ(sVb[KBUF]);                                                         \
    } while (0)

    // Q fragments (B-operand: col=q=fr, k=d), 2 q-subtiles per wave
    bf16x8 qf[2][2];
#pragma unroll
    for (int qb = 0; qb < 2; qb++)
#pragma unroll
        for (int ks = 0; ks < 2; ks++)
            qf[ks][qb] = *reinterpret_cast<const bf16x8*>(
                Q + base + (size_t)(q0 + 32 * w + 16 * qb + fr) * 64 + ks * 32 + fg * 8);

    const bf16 one = (bf16)1.0f;
    const bf16x8 ones = {one, one, one, one, one, one, one, one};

    const f32x4 zero = {0.f, 0.f, 0.f, 0.f};
    f32x4 o[4][2];
#pragma unroll
    for (int db = 0; db < 4; db++)
#pragma unroll
        for (int qb = 0; qb < 2; qb++) o[db][qb] = zero;
    f32x4 lacc[2] = {zero, zero};

    f32x4  scA[4][2], scB[4][2];
    bf16x8 vf[2][4];
    bf16x8 pf[2][2];
    unsigned int cc[2][4][2];

    // ---- prologue: tile 0 -> scA, vf[0]; no softmax/PV yet ----
    STAGE(0, 0);
    __syncthreads();                 // tile 0 ready
    STAGE(1, 64);
    {   // QK[0] only
#pragma unroll
        for (int kvb = 0; kvb < 4; kvb++) {
            const bf16x8 kf0 = *reinterpret_cast<const bf16x8*>(sKb[0] + ko0 + kvb * 1024);
            const bf16x8 kf1 = *reinterpret_cast<const bf16x8*>(sKb[0] + ko1 + kvb * 1024);
#pragma unroll
            for (int qb = 0; qb < 2; qb++) {
                scA[kvb][qb] = MFMA16(kf0, qf[0][qb], zero);
                scA[kvb][qb] = MFMA16(kf1, qf[1][qb], scA[kvb][qb]);
            }
        }
    }
    VF_READ(sVb[0]);

    // ---- main loop: tiles 1..62 as 31 unrolled pairs (static sc buffers) ----
    int t = 64;
    for (int i = 0; i < 31; i++, t += 128) {
        BODY(1, t, scB, scA);        // QK[odd] || SM[even]; PV[even]
        BODY(0, t + 64, scA, scB);   // QK[even] || SM[odd]; PV[odd]
    }

    // ---- tail: tile 63 (buf1): QK[63]||SM[62]; PV[62]; vf[63]; SM[63]; PV[63]
    __syncthreads();
    __builtin_amdgcn_s_setprio(1);
    QKSM_TILE(sKb[1], scB, scA);
    PERMPACK();
    PV_TILE();
    __builtin_amdgcn_s_setprio(0);
    VF_READ(sVb[1]);
    SOFTMAX_FULL(scB);
    __builtin_amdgcn_s_setprio(1);
    PV_TILE();
    __builtin_amdgcn_s_setprio(0);

    // epilogue: lane owns q = q0+32w+16qb+fr (col), d = 16db+4fg+r (rows)
    const int bb = bh >> 3, hh = bh & 7;
#pragma unroll
    for (int qb = 0; qb < 2; qb++) {
        const float inv = 1.0f / lacc[qb][0];
        const int s = q0 + 32 * w + 16 * qb + fr;
#pragma unroll
        for (int db = 0; db < 4; db++) {
            u32x2 pr = {cvtpk(o[db][qb][0] * inv, o[db][qb][1] * inv),
                        cvtpk(o[db][qb][2] * inv, o[db][qb][3] * inv)};
            *reinterpret_cast<u32x2*>(
                &ctx[((size_t)(bb * 4096 + s)) * 512 + hh * 64 + db * 16 + 4 * fg]) = pr;
        }
    }
#undef STAGE
#undef QKSM_TILE
#undef PERMPACK
#undef PV_TILE
#undef VF_READ
#undef SOFTMAX_FULL
#undef BODY
}

// ---------------- launch ----------------
extern "C" void kernel_launch(void* const* d_in, const int* in_sizes, int n_in,
                              void* d_out, int out_size, void* d_ws, size_t ws_size,
                              hipStream_t stream) {
    const float* X  = (const float*)d_in[0];
    const float* Wq = (const float*)d_in[1];
    const float* bq = (const float*)d_in[2];
    const float* Wk = (const float*)d_in[3];
    const float* bk = (const float*)d_in[4];
    const float* Wv = (const float*)d_in[5];
    const float* bv = (const float*)d_in[6];
    const float* Wo = (const float*)d_in[7];
    const float* bo = (const float*)d_in[8];
    float* out = (float*)d_out;

    bf16* ws  = (bf16*)d_ws;
    bf16* Xbf = ws;                    // 4,194,304
    bf16* Wqb = Xbf + 4194304;         // 4 x 262,144 contiguous (Wq,Wk,Wv,Wo)
    bf16* Qb  = Wqb + 4 * 262144;      // Q / K / Vt each 4,194,304
    bf16* Kb  = Qb + 4194304;
    bf16* Vtb = Kb + 4194304;
    bf16* Ctx = Vtb + 4194304;

    cvt_f32_bf16<<<4096, 256, 0, stream>>>(X, Xbf, 4194304);
    cvt_w4<<<dim3(256, 4), 256, 0, stream>>>(Wq, Wk, Wv, Wo, Wqb);

    // projections: Q (log2-scaled, head-split), K (head-split), V -> Vt[bh][d][s]
    gemm_bt<0><<<768, 256, 0, stream>>>(Xbf, Wqb, bq, bk, bv, Qb, nullptr);

    // flash attention -> ctx bf16 [B][S][H]
    attn_kernel<<<dim3(32, 16), 256, 0, stream>>>(Qb, Kb, Vtb, Ctx);

    // output projection -> fp32 d_out
    gemm_bt<1><<<256, 256, 0, stream>>>(Ctx, Wqb + 3 * 262144, bo,
                                        nullptr, nullptr, nullptr, out);
}

// Round 17
// 130.787 us; speedup vs baseline: 1.0807x; 1.0419x over previous
//
#include <hip/hip_runtime.h>
#include <hip/hip_bf16.h>
#include <math.h>

// B=2, S=4096, H=512, NH=8, HD=64. M = B*S = 8192.
// bf16 MFMA 16x16x32, fp32 accumulate. Softmax in exp2 domain (Q pre-scaled
// by 0.125*log2(e)). No running max: scores bounded, P=exp2(s), normalize at
// the end. Attention: 3-stage single-wave pipeline (QK[t] MFMA interleaved
// with softmax[t-1] VALU; then permlane, PV[t-1], vf[t]; sc double-buffered).
// gemm<1> uses BN=64 tiles (512 blocks -> 2 blocks/CU) for 2 waves/SIMD.
// Both fp32->bf16 converts merged into one kernel (one fewer dispatch).

typedef __bf16 bf16;
typedef __bf16 bf16x2v __attribute__((ext_vector_type(2)));
typedef __bf16 bf16x4 __attribute__((ext_vector_type(4)));
typedef __bf16 bf16x8 __attribute__((ext_vector_type(8)));
typedef float  f32x4  __attribute__((ext_vector_type(4)));
typedef unsigned int u32x2 __attribute__((ext_vector_type(2)));
typedef unsigned int u32x4 __attribute__((ext_vector_type(4)));

#define MFMA16(a, b, c) __builtin_amdgcn_mfma_f32_16x16x32_bf16((a), (b), (c), 0, 0, 0)

__device__ __forceinline__ void gll16(const bf16* g, bf16* l) {
    __builtin_amdgcn_global_load_lds(
        (const __attribute__((address_space(1))) void*)g,
        (__attribute__((address_space(3))) void*)l, 16, 0, 0);
}

__device__ __forceinline__ unsigned int cvtpk(float lo, float hi) {
    unsigned int r;
    asm("v_cvt_pk_bf16_f32 %0, %1, %2" : "=v"(r) : "v"(lo), "v"(hi));
    return r;
}

// ---------------- fp32 -> bf16 converts (merged) ----------------
// blocks 0..4095: X (4,194,304 elems). blocks 4096..5119: Wq,Wk,Wv,Wo.
__global__ __launch_bounds__(256) void cvt_all(const float* __restrict__ X,
                                               const float* __restrict__ a,
                                               const float* __restrict__ b,
                                               const float* __restrict__ c,
                                               const float* __restrict__ d,
                                               bf16* __restrict__ Xbf,
                                               bf16* __restrict__ Wqb) {
    const int bid = blockIdx.x;
    if (bid < 4096) {
        const int i = (bid * 256 + threadIdx.x) * 4;
        float4 v = *reinterpret_cast<const float4*>(X + i);
        bf16x4 o = {(bf16)v.x, (bf16)v.y, (bf16)v.z, (bf16)v.w};
        *reinterpret_cast<bf16x4*>(Xbf + i) = o;
    } else {
        const int r = bid - 4096;            // 0..1023
        const int y = r >> 8;                // 0..3
        const float* src = (y == 0) ? a : (y == 1) ? b : (y == 2) ? c : d;
        const int i = ((r & 255) * 256 + threadIdx.x) * 4;
        float4 v = *reinterpret_cast<const float4*>(src + i);
        bf16x4 o = {(bf16)v.x, (bf16)v.y, (bf16)v.z, (bf16)v.w};
        *reinterpret_cast<bf16x4*>(Wqb + y * 262144 + i) = o;
    }
}

// ---------------- GEMM: C = A[M,K] * W[N,K]^T + bias ----------------
// MODE 0: QKV projection (768 blocks, BM=BN=128). z: 0=Q (scaled 0.125*log2e,
//         head-split), 1=K (head-split), 2=V transposed: Vt[bh][d][s].
// MODE 1: output projection (512 blocks, BM=128, BN=64 -> 2 blocks/CU),
//         fp32 out [M][512].
template <int MODE>
__global__ __launch_bounds__(256) void gemm_bt(const bf16* __restrict__ A,
                                               const bf16* __restrict__ W,
                                               const float* __restrict__ b0,
                                               const float* __restrict__ b1,
                                               const float* __restrict__ b2,
                                               bf16* __restrict__ dstbf,
                                               float* __restrict__ dstf) {
    __shared__ bf16 sA[128 * 64];
    __shared__ bf16 sB[128 * 64];

    const int tid = threadIdx.x;
    const int w   = tid >> 6;
    const int l   = tid & 63;

    // XCD-grouping remap (pure permutation of block ids)
    int bx, by, bz;
    if (MODE == 0) {
        int lin = (blockIdx.x & 7) * 96 + (blockIdx.x >> 3);   // 768 blocks
        const int rem = lin % 12;
        bx = rem & 3; bz = rem >> 2; by = lin / 12;
    } else {
        int lin = (blockIdx.x & 7) * 64 + (blockIdx.x >> 3);   // 512 blocks
        bx = lin & 7; by = lin >> 3; bz = 0;                   // 8 x 64 tiles
    }
    constexpr int BN = (MODE == 0) ? 128 : 64;
    constexpr int NI = (MODE == 0) ? 4 : 2;                    // 16-col frags/wave
    const int m0 = by * 128;
    const int n0 = bx * BN;
    const int z  = bz;

    const bf16*  Wz   = (MODE == 0) ? (W + z * 262144) : W;
    const float* bias = (MODE == 0) ? (z == 0 ? b0 : (z == 1 ? b1 : b2)) : b0;
    const float  scale = (MODE == 0 && z == 0) ? 0.125f * 1.4426950408889634f : 1.0f;

    const int wr = (w >> 1) * 64;
    const int wc = (w & 1) * (BN / 2);
    const int fr = l & 15, fg = l >> 4;

    // staging geometry
    const int srow0 = tid >> 3;                  // 0..31
    const int sgr   = (tid & 7) ^ (srow0 & 7);   // pre-swizzled source granule
    const int ldso  = srow0 * 64 + (tid & 7) * 8;

    f32x4 acc[4][NI];
    const f32x4 zero = {0.f, 0.f, 0.f, 0.f};
#pragma unroll
    for (int i = 0; i < 4; i++)
#pragma unroll
        for (int j = 0; j < NI; j++) acc[i][j] = zero;

    for (int kt = 0; kt < 512; kt += 64) {
        __syncthreads();
#pragma unroll
        for (int p = 0; p < 4; p++) {
            const int row = srow0 + 32 * p;
            gll16(A + (m0 + row) * 512 + kt + sgr * 8, &sA[p * 2048 + ldso]);
            if (MODE == 0 || p < 2)   // MODE 1: W tile is only 64 rows
                gll16(Wz + (n0 + row) * 512 + kt + sgr * 8, &sB[p * 2048 + ldso]);
        }
        __syncthreads();

#pragma unroll
        for (int ks = 0; ks < 2; ks++) {
            bf16x8 af[4], bfg[NI];
#pragma unroll
            for (int mi = 0; mi < 4; mi++)
                af[mi] = *reinterpret_cast<const bf16x8*>(
                    &sA[(wr + mi * 16 + fr) * 64 + (((4 * ks + fg) ^ (fr & 7)) << 3)]);
#pragma unroll
            for (int ni = 0; ni < NI; ni++)
                bfg[ni] = *reinterpret_cast<const bf16x8*>(
                    &sB[(wc + ni * 16 + fr) * 64 + (((4 * ks + fg) ^ (fr & 7)) << 3)]);
#pragma unroll
            for (int mi = 0; mi < 4; mi++)
#pragma unroll
                for (int ni = 0; ni < NI; ni++)
                    acc[mi][ni] = MFMA16(af[mi], bfg[ni], acc[mi][ni]);
        }
    }

#pragma unroll
    for (int mi = 0; mi < 4; mi++) {
#pragma unroll
        for (int ni = 0; ni < NI; ni++) {
            const int gcol = n0 + wc + ni * 16 + fr;
            const float bc = bias[gcol];
#pragma unroll
            for (int r = 0; r < 4; r++) {
                const int grow = m0 + wr + mi * 16 + fg * 4 + r;
                float v = acc[mi][ni][r] + bc;
                if (MODE == 0) {
                    v *= scale;
                    const int bb = grow >> 12, s = grow & 4095;
                    const int hh = gcol >> 6, dd = gcol & 63;
                    size_t idx;
                    if (z == 2) {
                        idx = (size_t)2 * 4194304 +
                              ((size_t)((bb * 8 + hh) * 64 + dd)) * 4096 + s;
                    } else {
                        idx = (size_t)z * 4194304 +
                              ((size_t)((bb * 8 + hh) * 4096 + s) << 6) + dd;
                    }
                    dstbf[idx] = (bf16)v;
                } else {
                    dstf[grow * 512 + gcol] = v;
                }
            }
        }
    }
}

// ---------------- Flash attention (3-stage pipelined, round-16 verified) ----
// 256 threads = 4 waves; each wave owns 32 q-rows (2 subtiles); block = 128
// q-rows x 4096 keys. grid 512 blocks, XCD-remapped. KV tile 64, dbuf
// global_load_lds. Per body (tile t): {QK[t] MFMA interleaved with
// softmax[t-1] exp2/cvtpk (independent)} -> permlane -> PV[t-1] -> vf[t].
__global__ __launch_bounds__(256, 2) void attn_kernel(const bf16* __restrict__ Q,
                                                      const bf16* __restrict__ K,
                                                      const bf16* __restrict__ Vt,
                                                      bf16* __restrict__ ctx) {
    __shared__ bf16 sKb[2][4096];     // [kv][d], 16B-granule XOR-swizzled
    __shared__ bf16 sVb[2][4096];     // [d][kv], swizzled

    const int tid = threadIdx.x;
    const int w   = tid >> 6;
    const int l   = tid & 63;
    const int fr  = l & 15, fg = l >> 4;

    // XCD-aware remap: 512 blocks -> 64 consecutive per XCD (= 2 heads)
    int n = blockIdx.y * 32 + blockIdx.x;
    n = (n & 7) * 64 + (n >> 3);
    const int bh  = n >> 5;
    const int q0  = (n & 31) * 128;
    const size_t base = (size_t)bh * 262144;

    const int srow0 = tid >> 3;
    const int sgr   = (tid & 7) ^ (srow0 & 7);
    const int ldso  = srow0 * 64 + (tid & 7) * 8;

    const int ko0 = fr * 64 + (((0 + fg) ^ (fr & 7)) << 3);
    const int ko1 = fr * 64 + (((4 + fg) ^ (fr & 7)) << 3);

#define STAGE(buf, tt)                                                              \
    do {                                                                            \
        _Pragma("unroll")                                                           \
        for (int p = 0; p < 2; p++) {                                               \
            const int row_ = srow0 + 32 * p;                                        \
            gll16(K  + base + (size_t)((tt) + row_) * 64 + sgr * 8,                 \
                  &sKb[buf][p * 2048 + ldso]);                                      \
            gll16(Vt + base + (size_t)row_ * 4096 + (tt) + sgr * 8,                 \
                  &sVb[buf][p * 2048 + ldso]);                                      \
        }                                                                           \
    } while (0)

// QK of current tile into SCN, interleaved with exp2/cvtpk of SCO (prev tile)
#define QKSM_TILE(kb_, SCN, SCO)                                                    \
    do {                                                                            \
        _Pragma("unroll")                                                           \
        for (int kvb = 0; kvb < 4; kvb++) {                                         \
            const bf16x8 kf0 = *reinterpret_cast<const bf16x8*>((kb_) + ko0 + kvb * 1024); \
            const bf16x8 kf1 = *reinterpret_cast<const bf16x8*>((kb_) + ko1 + kvb * 1024); \
            _Pragma("unroll")                                                       \
            for (int qb = 0; qb < 2; qb++) {                                        \
                SCN[kvb][qb] = MFMA16(kf0, qf[0][qb], zero);                        \
                SCN[kvb][qb] = MFMA16(kf1, qf[1][qb], SCN[kvb][qb]);                \
            }                                                                       \
            _Pragma("unroll")                                                       \
            for (int qb = 0; qb < 2; qb++) {                                        \
                cc[qb][kvb][0] = cvtpk(__builtin_amdgcn_exp2f(SCO[kvb][qb][0]),     \
                                       __builtin_amdgcn_exp2f(SCO[kvb][qb][1]));    \
                cc[qb][kvb][1] = cvtpk(__builtin_amdgcn_exp2f(SCO[kvb][qb][2]),     \
                                       __builtin_amdgcn_exp2f(SCO[kvb][qb][3]));    \
            }                                                                       \
        }                                                                           \
    } while (0)

// permlane redistribution: cc -> pf
#define PERMPACK()                                                                  \
    do {                                                                            \
        _Pragma("unroll")                                                           \
        for (int qb = 0; qb < 2; qb++) {                                            \
            _Pragma("unroll")                                                       \
            for (int ks = 0; ks < 2; ks++) {                                        \
                unsigned int a0 = cc[qb][2 * ks][0], b0 = cc[qb][2 * ks + 1][0];    \
                unsigned int a1 = cc[qb][2 * ks][1], b1 = cc[qb][2 * ks + 1][1];    \
                asm("v_permlane32_swap_b32 %0, %1" : "+v"(a0), "+v"(b0));           \
                asm("v_permlane16_swap_b32 %0, %1" : "+v"(a0), "+v"(b0));           \
                asm("v_permlane32_swap_b32 %0, %1" : "+v"(a1), "+v"(b1));           \
                asm("v_permlane16_swap_b32 %0, %1" : "+v"(a1), "+v"(b1));           \
                u32x4 uu = {a0, a1, b0, b1};                                        \
                pf[ks][qb] = __builtin_bit_cast(bf16x8, uu);                        \
            }                                                                       \
        }                                                                           \
    } while (0)

#define PV_TILE()                                                                   \
    do {                                                                            \
        _Pragma("unroll")                                                           \
        for (int ks = 0; ks < 2; ks++) {                                            \
            _Pragma("unroll")                                                       \
            for (int qb = 0; qb < 2; qb++)                                          \
                lacc[qb] = MFMA16(ones, pf[ks][qb], lacc[qb]);                      \
            _Pragma("unroll")                                                       \
            for (int db = 0; db < 4; db++)                                          \
                _Pragma("unroll")                                                   \
                for (int qb = 0; qb < 2; qb++)                                      \
                    o[db][qb] = MFMA16(vf[ks][db], pf[ks][qb], o[db][qb]);          \
        }                                                                           \
    } while (0)

#define VF_READ(vb_)                                                                \
    do {                                                                            \
        _Pragma("unroll")                                                           \
        for (int db = 0; db < 4; db++) {                                            \
            vf[0][db] = *reinterpret_cast<const bf16x8*>((vb_) + ko0 + db * 1024);  \
            vf[1][db] = *reinterpret_cast<const bf16x8*>((vb_) + ko1 + db * 1024);  \
        }                                                                           \
    } while (0)

// full softmax of SC (exp2+cvtpk+permlane) -> pf  (tail only)
#define SOFTMAX_FULL(SC)                                                            \
    do {                                                                            \
        _Pragma("unroll")                                                           \
        for (int qb = 0; qb < 2; qb++)                                              \
            _Pragma("unroll")                                                       \
            for (int kvb = 0; kvb < 4; kvb++) {                                     \
                cc[qb][kvb][0] = cvtpk(__builtin_amdgcn_exp2f(SC[kvb][qb][0]),      \
                                       __builtin_amdgcn_exp2f(SC[kvb][qb][1]));     \
                cc[qb][kvb][1] = cvtpk(__builtin_amdgcn_exp2f(SC[kvb][qb][2]),      \
                                       __builtin_amdgcn_exp2f(SC[kvb][qb][3]));     \
            }                                                                       \
        PERMPACK();                                                                 \
    } while (0)

// body for tile tt: QK[tt] || SM[tt-1] -> pf; PV[tt-1]; vf[tt]
#define BODY(KBUF, tt, SCN, SCO)                                                    \
    do {                                                                            \
        __syncthreads();                                                            \
        STAGE((KBUF) ^ 1, (tt) + 64);                                               \
        __builtin_amdgcn_s_setprio(1);                                              \
        QKSM_TILE(sKb[KBUF], SCN, SCO);                                             \
        PERMPACK();                                                                 \
        PV_TILE();                                                                  \
        __builtin_amdgcn_s_setprio(0);                                              \
        VF_READ(sVb[KBUF]);                                                         \
    } while (0)

    // Q fragments (B-operand: col=q=fr, k=d), 2 q-subtiles per wave
    bf16x8 qf[2][2];
#pragma unroll
    for (int qb = 0; qb < 2; qb++)
#pragma unroll
        for (int ks = 0; ks < 2; ks++)
            qf[ks][qb] = *reinterpret_cast<const bf16x8*>(
                Q + base + (size_t)(q0 + 32 * w + 16 * qb + fr) * 64 + ks * 32 + fg * 8);

    const bf16 one = (bf16)1.0f;
    const bf16x8 ones = {one, one, one, one, one, one, one, one};

    const f32x4 zero = {0.f, 0.f, 0.f, 0.f};
    f32x4 o[4][2];
#pragma unroll
    for (int db = 0; db < 4; db++)
#pragma unroll
        for (int qb = 0; qb < 2; qb++) o[db][qb] = zero;
    f32x4 lacc[2] = {zero, zero};

    f32x4  scA[4][2], scB[4][2];
    bf16x8 vf[2][4];
    bf16x8 pf[2][2];
    unsigned int cc[2][4][2];

    // ---- prologue: tile 0 -> scA, vf[0]; no softmax/PV yet ----
    STAGE(0, 0);
    __syncthreads();                 // tile 0 ready
    STAGE(1, 64);
    {   // QK[0] only
#pragma unroll
        for (int kvb = 0; kvb < 4; kvb++) {
            const bf16x8 kf0 = *reinterpret_cast<const bf16x8*>(sKb[0] + ko0 + kvb * 1024);
            const bf16x8 kf1 = *reinterpret_cast<const bf16x8*>(sKb[0] + ko1 + kvb * 1024);
#pragma unroll
            for (int qb = 0; qb < 2; qb++) {
                scA[kvb][qb] = MFMA16(kf0, qf[0][qb], zero);
                scA[kvb][qb] = MFMA16(kf1, qf[1][qb], scA[kvb][qb]);
            }
        }
    }
    VF_READ(sVb[0]);

    // ---- main loop: tiles 1..62 as 31 unrolled pairs (static sc buffers) ----
    int t = 64;
    for (int i = 0; i < 31; i++, t += 128) {
        BODY(1, t, scB, scA);        // QK[odd] || SM[even]; PV[even]
        BODY(0, t + 64, scA, scB);   // QK[even] || SM[odd]; PV[odd]
    }

    // ---- tail: tile 63 (buf1): QK[63]||SM[62]; PV[62]; vf[63]; SM[63]; PV[63]
    __syncthreads();
    __builtin_amdgcn_s_setprio(1);
    QKSM_TILE(sKb[1], scB, scA);
    PERMPACK();
    PV_TILE();
    __builtin_amdgcn_s_setprio(0);
    VF_READ(sVb[1]);
    SOFTMAX_FULL(scB);
    __builtin_amdgcn_s_setprio(1);
    PV_TILE();
    __builtin_amdgcn_s_setprio(0);

    // epilogue: lane owns q = q0+32w+16qb+fr (col), d = 16db+4fg+r (rows)
    const int bb = bh >> 3, hh = bh & 7;
#pragma unroll
    for (int qb = 0; qb < 2; qb++) {
        const float inv = 1.0f / lacc[qb][0];
        const int s = q0 + 32 * w + 16 * qb + fr;
#pragma unroll
        for (int db = 0; db < 4; db++) {
            u32x2 pr = {cvtpk(o[db][qb][0] * inv, o[db][qb][1] * inv),
                        cvtpk(o[db][qb][2] * inv, o[db][qb][3] * inv)};
            *reinterpret_cast<u32x2*>(
                &ctx[((size_t)(bb * 4096 + s)) * 512 + hh * 64 + db * 16 + 4 * fg]) = pr;
        }
    }
#undef STAGE
#undef QKSM_TILE
#undef PERMPACK
#undef PV_TILE
#undef VF_READ
#undef SOFTMAX_FULL
#undef BODY
}

// ---------------- launch ----------------
extern "C" void kernel_launch(void* const* d_in, const int* in_sizes, int n_in,
                              void* d_out, int out_size, void* d_ws, size_t ws_size,
                              hipStream_t stream) {
    const float* X  = (const float*)d_in[0];
    const float* Wq = (const float*)d_in[1];
    const float* bq = (const float*)d_in[2];
    const float* Wk = (const float*)d_in[3];
    const float* bk = (const float*)d_in[4];
    const float* Wv = (const float*)d_in[5];
    const float* bv = (const float*)d_in[6];
    const float* Wo = (const float*)d_in[7];
    const float* bo = (const float*)d_in[8];
    float* out = (float*)d_out;

    bf16* ws  = (bf16*)d_ws;
    bf16* Xbf = ws;                    // 4,194,304
    bf16* Wqb = Xbf + 4194304;         // 4 x 262,144 contiguous (Wq,Wk,Wv,Wo)
    bf16* Qb  = Wqb + 4 * 262144;      // Q / K / Vt each 4,194,304
    bf16* Kb  = Qb + 4194304;
    bf16* Vtb = Kb + 4194304;
    bf16* Ctx = Vtb + 4194304;

    // X + all weights -> bf16 in one kernel
    cvt_all<<<5120, 256, 0, stream>>>(X, Wq, Wk, Wv, Wo, Xbf, Wqb);

    // projections: Q (log2-scaled, head-split), K (head-split), V -> Vt[bh][d][s]
    gemm_bt<0><<<768, 256, 0, stream>>>(Xbf, Wqb, bq, bk, bv, Qb, nullptr);

    // flash attention -> ctx bf16 [B][S][H]
    attn_kernel<<<dim3(32, 16), 256, 0, stream>>>(Qb, Kb, Vtb, Ctx);

    // output projection (BN=64, 512 blocks) -> fp32 d_out
    gemm_bt<1><<<512, 256, 0, stream>>>(Ctx, Wqb + 3 * 262144, bo,
                                        nullptr, nullptr, nullptr, out);
}